// Round 9
// baseline (97.904 us; speedup 1.0000x reference)
//
#include <hip/hip_runtime.h>
#include <math.h>

#define HID    1024
#define VOCAB  50257
#define MAXLEN 2048
#define SMB 256                              // softmax_apply blocks
#define SMR (MAXLEN / SMB)                   // 8 rows per block
#define LROWS 64                             // rows per logits block (8 waves x 8)
#define LBLK ((VOCAB + LROWS - 1) / LROWS)   // 786

// ---------------- ws layout (float indices) ----------------
#define WS_SCORES    0        // 2048
#define WS_APPLIED   4096     // 1024
#define WS_X         5120     // 1024
#define WS_GH        6144     // 3072
#define WS_HNEW      12288    // 1024
#define WS_CTR       14336    // 1 uint
#define WS_PM        16384    // 786
#define WS_PS        20480    // 786
#define WS_PARTIALS  32768    // 256 x 1024

__device__ inline float wave_reduce_sum(float v) {
    #pragma unroll
    for (int m = 32; m > 0; m >>= 1) v += __shfl_xor(v, m, 64);
    return v;
}

// K1: blocks [0,256): attn scores, 2 rows/wave (2048 rows, 2048 cols);
//     blocks [256,640): gh = W_hh@h + b_hh, 2 rows/wave (3072 rows, 1024 cols).
//     Block 0 also resets the spin counter used by K3 (device-scope store;
//     stream order guarantees it lands before K3 launches).
__global__ __launch_bounds__(256) void k_scores_gh(
        const float* __restrict__ emb, const int* __restrict__ tok,
        const float* __restrict__ hidden,
        const float* __restrict__ attn_W, const float* __restrict__ attn_b,
        const float* __restrict__ W_hh, const float* __restrict__ b_hh,
        float* __restrict__ scores, float* __restrict__ gh,
        unsigned int* __restrict__ ctr) {
    if (blockIdx.x == 0 && threadIdx.x == 0)
        __hip_atomic_store(ctr, 0u, __ATOMIC_RELAXED, __HIP_MEMORY_SCOPE_AGENT);
    int wib = threadIdx.x >> 6, lane = threadIdx.x & 63;
    int wtask = blockIdx.x * 4 + wib;
    if (blockIdx.x < 256) {
        int r0 = wtask * 2;
        const float* erow = emb + (size_t)tok[0] * HID;
        const float* w0 = attn_W + (size_t)r0 * (2 * HID);
        const float* w1 = w0 + 2 * HID;
        float a0 = 0.f, a1 = 0.f;
        #pragma unroll
        for (int i = 0; i < 8; ++i) {
            int k = i * 256 + lane * 4;
            float4 c = (k < HID) ? *(const float4*)(erow + k)
                                 : *(const float4*)(hidden + (k - HID));
            float4 p = *(const float4*)(w0 + k);
            float4 q = *(const float4*)(w1 + k);
            a0 += p.x * c.x + p.y * c.y + p.z * c.z + p.w * c.w;
            a1 += q.x * c.x + q.y * c.y + q.z * c.z + q.w * c.w;
        }
        a0 = wave_reduce_sum(a0);
        a1 = wave_reduce_sum(a1);
        if (lane == 0) {
            scores[r0]     = a0 + attn_b[r0];
            scores[r0 + 1] = a1 + attn_b[r0 + 1];
        }
    } else {
        int r0 = (wtask - 1024) * 2;   // [0, 3072) step 2
        const float* w0 = W_hh + (size_t)r0 * HID;
        const float* w1 = w0 + HID;
        float a0 = 0.f, a1 = 0.f;
        #pragma unroll
        for (int i = 0; i < 4; ++i) {
            int k = i * 256 + lane * 4;
            float4 c = *(const float4*)(hidden + k);
            float4 p = *(const float4*)(w0 + k);
            float4 q = *(const float4*)(w1 + k);
            a0 += p.x * c.x + p.y * c.y + p.z * c.z + p.w * c.w;
            a1 += q.x * c.x + q.y * c.y + q.z * c.z + q.w * c.w;
        }
        a0 = wave_reduce_sum(a0);
        a1 = wave_reduce_sum(a1);
        if (lane == 0) {
            gh[r0]     = a0 + b_hh[r0];
            gh[r0 + 1] = a1 + b_hh[r0 + 1];
        }
    }
}

// K2: fused softmax(2048) + partial weighted sum of encoder rows.
__global__ __launch_bounds__(256) void k_softmax_apply(
        const float* __restrict__ scores, const float* __restrict__ E,
        float* __restrict__ out_w, float* __restrict__ partials) {
    __shared__ float red[256];
    __shared__ float wrow[SMR];
    int t = threadIdx.x, b = blockIdx.x;
    float v[8];
    float m = -INFINITY;
    #pragma unroll
    for (int i = 0; i < 8; ++i) { v[i] = scores[t + 256 * i]; m = fmaxf(m, v[i]); }
    red[t] = m; __syncthreads();
    for (int s = 128; s > 0; s >>= 1) { if (t < s) red[t] = fmaxf(red[t], red[t + s]); __syncthreads(); }
    float M = red[0]; __syncthreads();
    float s = 0.f;
    #pragma unroll
    for (int i = 0; i < 8; ++i) s += expf(v[i] - M);
    red[t] = s; __syncthreads();
    for (int k = 128; k > 0; k >>= 1) { if (t < k) red[t] += red[t + k]; __syncthreads(); }
    float invS = 1.f / red[0];
    int r0 = b * SMR;
    if (t < SMR) wrow[t] = expf(scores[r0 + t] - M) * invS;
    __syncthreads();
    int j = t * 4;
    float4 acc = make_float4(0.f, 0.f, 0.f, 0.f);
    #pragma unroll
    for (int r = 0; r < SMR; ++r) {
        float w = wrow[r];
        float4 e = *(const float4*)(E + (size_t)(r0 + r) * HID + j);
        acc.x += w * e.x; acc.y += w * e.y; acc.z += w * e.z; acc.w += w * e.w;
    }
    *(float4*)(partials + (size_t)b * HID + j) = acc;
    if (b == 0) {
        #pragma unroll
        for (int i = 0; i < 8; ++i) out_w[t + 256 * i] = expf(v[i] - M) * invS;
    }
}

// K3: merged reduce + comb. Blocks [0,32): reduce 256 partial rows -> applied,
// then arrive (atomicAdd, device scope). Blocks [32,288): compute the
// embedded-half of comb's dot first (hides the wait), spin until all 32
// reducers arrived (acquire, agent scope), then finish with the applied-half.
__global__ __launch_bounds__(256) void k_reduce_comb(
        const float* __restrict__ partials,
        const float* __restrict__ emb, const int* __restrict__ tok,
        const float* __restrict__ comb_W, const float* __restrict__ comb_b,
        float* __restrict__ applied, float* __restrict__ x,
        unsigned int* __restrict__ ctr) {
    if (blockIdx.x < 32) {
        __shared__ float red[256];
        int t = threadIdx.x;
        int co = t & 31, grp = t >> 5;
        int col = blockIdx.x * 32 + co;
        float acc = 0.f;
        #pragma unroll
        for (int cc = 0; cc < 32; ++cc)
            acc += partials[(size_t)(grp * 32 + cc) * HID + col];
        red[grp * 32 + co] = acc;
        __syncthreads();
        if (t < 32) {
            float s = 0.f;
            #pragma unroll
            for (int g = 0; g < 8; ++g) s += red[g * 32 + t];
            applied[blockIdx.x * 32 + t] = s;
        }
        __threadfence();
        __syncthreads();
        if (t == 0)
            __hip_atomic_fetch_add(ctr, 1u, __ATOMIC_RELEASE, __HIP_MEMORY_SCOPE_AGENT);
    } else {
        int wib = threadIdx.x >> 6, lane = threadIdx.x & 63;
        int row = (blockIdx.x - 32) * 4 + wib;
        const float* erow = emb + (size_t)tok[0] * HID;
        const float* wrow = comb_W + (size_t)row * (2 * HID);
        float acc = 0.f;
        #pragma unroll
        for (int i = 0; i < 4; ++i) {          // embedded half: k in [0,1024)
            int k = i * 256 + lane * 4;
            float4 w = *(const float4*)(wrow + k);
            float4 c = *(const float4*)(erow + k);
            acc += w.x * c.x + w.y * c.y + w.z * c.z + w.w * c.w;
        }
        if (threadIdx.x == 0) {
            while (__hip_atomic_load(ctr, __ATOMIC_ACQUIRE, __HIP_MEMORY_SCOPE_AGENT) < 32u)
                __builtin_amdgcn_s_sleep(2);
        }
        __syncthreads();
        #pragma unroll
        for (int i = 4; i < 8; ++i) {          // applied half: k in [1024,2048)
            int k = i * 256 + lane * 4;
            float4 w = *(const float4*)(wrow + k);
            float4 c = *(const float4*)(applied + (k - HID));
            acc += w.x * c.x + w.y * c.y + w.z * c.z + w.w * c.w;
        }
        acc = wave_reduce_sum(acc);
        if (lane == 0) x[row] = fmaxf(acc + comb_b[row], 0.f);
    }
}

// K4: fused gi-GEMV + GRU gate. Block = 384 thr = 6 waves = 2 hidden units.
__global__ __launch_bounds__(384) void k_gru_fused(
        const float* __restrict__ W_ih, const float* __restrict__ b_ih,
        const float* __restrict__ x, const float* __restrict__ gh,
        const float* __restrict__ h,
        float* __restrict__ hnew_out, float* __restrict__ hnew_ws) {
    __shared__ float sm[6];
    int w = threadIdx.x >> 6, lane = threadIdx.x & 63;
    int hid = blockIdx.x * 2 + (w >= 3 ? 1 : 0);
    int gate = w % 3;  // 0=r, 1=z, 2=n
    int row = gate * HID + hid;
    const float* wrow = W_ih + (size_t)row * HID;
    float acc = 0.f;
    #pragma unroll
    for (int i = 0; i < 4; ++i) {
        int k = i * 256 + lane * 4;
        float4 a = *(const float4*)(wrow + k);
        float4 c = *(const float4*)(x + k);
        acc += a.x * c.x + a.y * c.y + a.z * c.z + a.w * c.w;
    }
    acc = wave_reduce_sum(acc);
    if (lane == 0) sm[w] = acc + b_ih[row];
    __syncthreads();
    if (threadIdx.x == 0 || threadIdx.x == 192) {
        int base = (threadIdx.x == 0) ? 0 : 3;
        int i = blockIdx.x * 2 + (base ? 1 : 0);
        float gir = sm[base + 0], giz = sm[base + 1], gin = sm[base + 2];
        float r = 1.f / (1.f + expf(-(gir + gh[i])));
        float z = 1.f / (1.f + expf(-(giz + gh[i + HID])));
        float n = tanhf(gin + r * gh[i + 2 * HID]);
        float hn = (1.f - z) * n + z * h[i];
        hnew_out[i] = hn;
        hnew_ws[i]  = hn;
    }
}

// K5: logits + per-block online-LSE (m,s). 8 waves/block, 8 rows/wave.
__global__ __launch_bounds__(512) void k_logits(
        const float* __restrict__ hnew, const float* __restrict__ out_W,
        const float* __restrict__ out_b,
        float* __restrict__ logits, float* __restrict__ pm, float* __restrict__ ps) {
    __shared__ float wm[8], wsum[8];
    int wib = threadIdx.x >> 6, lane = threadIdx.x & 63;
    int r0 = blockIdx.x * LROWS + wib * 8;
    bool val[8]; int rr[8];
    #pragma unroll
    for (int j = 0; j < 8; ++j) {
        val[j] = (r0 + j) < VOCAB;
        rr[j] = val[j] ? (r0 + j) : 0;
    }
    float acc[8] = {0.f, 0.f, 0.f, 0.f, 0.f, 0.f, 0.f, 0.f};
    #pragma unroll
    for (int i = 0; i < 4; ++i) {
        int k = i * 256 + lane * 4;
        float4 c = *(const float4*)(hnew + k);
        #pragma unroll
        for (int j = 0; j < 8; ++j) {
            float4 a = *(const float4*)(out_W + (size_t)rr[j] * HID + k);
            acc[j] += a.x * c.x + a.y * c.y + a.z * c.z + a.w * c.w;
        }
    }
    #pragma unroll
    for (int j = 0; j < 8; ++j) acc[j] = wave_reduce_sum(acc[j]);
    if (lane == 0) {
        float l[8], m = -INFINITY;
        #pragma unroll
        for (int j = 0; j < 8; ++j) {
            l[j] = acc[j] + out_b[rr[j]];
            if (val[j]) { logits[r0 + j] = l[j]; m = fmaxf(m, l[j]); }
        }
        float s = 0.f;
        #pragma unroll
        for (int j = 0; j < 8; ++j) if (val[j]) s += expf(l[j] - m);
        wm[wib] = m; wsum[wib] = s;
    }
    __syncthreads();
    if (threadIdx.x == 0) {
        float M = wm[0];
        #pragma unroll
        for (int i = 1; i < 8; ++i) M = fmaxf(M, wm[i]);
        float S = 0.f;
        #pragma unroll
        for (int i = 0; i < 8; ++i) S += (wsum[i] > 0.f) ? wsum[i] * expf(wm[i] - M) : 0.f;
        pm[blockIdx.x] = M;
        ps[blockIdx.x] = S;
    }
}

// K6: every block redundantly merges the LBLK (m,s) pairs (bit-identical ->
// deterministic), then writes out[v] = logits[v] - lse for its slice.
__global__ __launch_bounds__(256) void k_logsoftmax_write(
        const float* __restrict__ pm, const float* __restrict__ ps,
        float* __restrict__ out) {
    __shared__ float red[256];
    int t = threadIdx.x;
    float m = -INFINITY;
    for (int i = t; i < LBLK; i += 256) m = fmaxf(m, pm[i]);
    red[t] = m; __syncthreads();
    for (int s = 128; s > 0; s >>= 1) { if (t < s) red[t] = fmaxf(red[t], red[t + s]); __syncthreads(); }
    float M = red[0]; __syncthreads();
    float acc = 0.f;
    for (int i = t; i < LBLK; i += 256) acc += ps[i] * expf(pm[i] - M);
    red[t] = acc; __syncthreads();
    for (int s = 128; s > 0; s >>= 1) { if (t < s) red[t] += red[t + s]; __syncthreads(); }
    float lse = M + logf(red[0]);
    int v = blockIdx.x * 256 + t;
    if (v < VOCAB) out[v] -= lse;
}

extern "C" void kernel_launch(void* const* d_in, const int* in_sizes, int n_in,
                              void* d_out, int out_size, void* d_ws, size_t ws_size,
                              hipStream_t stream) {
    const int*   tok     = (const int*)d_in[0];
    const float* hidden  = (const float*)d_in[1];
    const float* E       = (const float*)d_in[2];
    const float* emb     = (const float*)d_in[3];
    const float* attn_W  = (const float*)d_in[4];
    const float* attn_b  = (const float*)d_in[5];
    const float* comb_W  = (const float*)d_in[6];
    const float* comb_b  = (const float*)d_in[7];
    const float* W_ih    = (const float*)d_in[8];
    const float* W_hh    = (const float*)d_in[9];
    const float* b_ih    = (const float*)d_in[10];
    const float* b_hh    = (const float*)d_in[11];
    const float* out_W   = (const float*)d_in[12];
    const float* out_b   = (const float*)d_in[13];

    float* out       = (float*)d_out;          // [0, VOCAB): log-probs
    float* hnew_out  = out + VOCAB;            // h_new
    float* attnw_out = out + VOCAB + HID;      // attn_weights

    float* ws        = (float*)d_ws;
    float* scores    = ws + WS_SCORES;
    float* applied   = ws + WS_APPLIED;
    float* x         = ws + WS_X;
    float* gh        = ws + WS_GH;
    float* hnew_ws   = ws + WS_HNEW;
    unsigned int* ctr = (unsigned int*)(ws + WS_CTR);
    float* pm        = ws + WS_PM;
    float* ps        = ws + WS_PS;
    float* partials  = ws + WS_PARTIALS;

    k_scores_gh<<<640, 256, 0, stream>>>(emb, tok, hidden, attn_W, attn_b,
                                         W_hh, b_hh, scores, gh, ctr);
    k_softmax_apply<<<SMB, 256, 0, stream>>>(scores, E, attnw_out, partials);
    k_reduce_comb<<<288, 256, 0, stream>>>(partials, emb, tok, comb_W, comb_b,
                                           applied, x, ctr);
    k_gru_fused<<<512, 384, 0, stream>>>(W_ih, b_ih, x, gh, hidden, hnew_out, hnew_ws);
    k_logits<<<LBLK, 512, 0, stream>>>(hnew_ws, out_W, out_b, out, pm, ps);
    k_logsoftmax_write<<<(VOCAB + 255) / 256, 256, 0, stream>>>(pm, ps, out);
}

// Round 10
// 68.354 us; speedup vs baseline: 1.4323x; 1.4323x over previous
//
#include <hip/hip_runtime.h>
#include <math.h>

#define HID    1024
#define VOCAB  50257
#define MAXLEN 2048
#define SMB 256                          // softmax_apply blocks
#define SMR (MAXLEN / SMB)               // 8 rows per block
#define LROWS 16                         // rows per logits block
#define LBLK ((VOCAB + LROWS - 1) / LROWS)  // 3142

// ---------------- ws layout (float indices) ----------------
#define WS_SCORES    0
#define WS_APPLIED   4096
#define WS_X         5120
#define WS_GI        6144
#define WS_GH        9216
#define WS_HNEW      12288
#define WS_PM        16384
#define WS_PS        30720
#define WS_PARTIALS  49152

__device__ inline float wave_reduce_sum(float v) {
    #pragma unroll
    for (int m = 32; m > 0; m >>= 1) v += __shfl_xor(v, m, 64);
    return v;
}

// K1: scores[l] = dot(cat(embedded, h), attn_W[l]) + attn_b[l]; one wave per row
__global__ __launch_bounds__(256) void k_attn_scores(
        const float* __restrict__ emb, const int* __restrict__ tok,
        const float* __restrict__ hidden,
        const float* __restrict__ attn_W, const float* __restrict__ attn_b,
        float* __restrict__ scores) {
    int gtid = blockIdx.x * blockDim.x + threadIdx.x;
    int row = gtid >> 6, lane = gtid & 63;
    if (row >= MAXLEN) return;
    const float* erow = emb + (size_t)tok[0] * HID;
    const float* wrow = attn_W + (size_t)row * (2 * HID);
    float acc = 0.f;
    #pragma unroll
    for (int i = 0; i < 8; ++i) {
        int k = i * 256 + lane * 4;
        float4 w = *(const float4*)(wrow + k);
        float4 c = (k < HID) ? *(const float4*)(erow + k)
                             : *(const float4*)(hidden + (k - HID));
        acc += w.x * c.x + w.y * c.y + w.z * c.z + w.w * c.w;
    }
    acc = wave_reduce_sum(acc);
    if (lane == 0) scores[row] = acc + attn_b[row];
}

// K2: fused softmax(2048) + partial weighted sum of encoder rows.
__global__ __launch_bounds__(256) void k_softmax_apply(
        const float* __restrict__ scores, const float* __restrict__ E,
        float* __restrict__ out_w, float* __restrict__ partials) {
    __shared__ float red[256];
    __shared__ float wrow[SMR];
    int t = threadIdx.x, b = blockIdx.x;
    float v[8];
    float m = -INFINITY;
    #pragma unroll
    for (int i = 0; i < 8; ++i) { v[i] = scores[t + 256 * i]; m = fmaxf(m, v[i]); }
    red[t] = m; __syncthreads();
    for (int s = 128; s > 0; s >>= 1) { if (t < s) red[t] = fmaxf(red[t], red[t + s]); __syncthreads(); }
    float M = red[0]; __syncthreads();
    float s = 0.f;
    #pragma unroll
    for (int i = 0; i < 8; ++i) s += expf(v[i] - M);
    red[t] = s; __syncthreads();
    for (int k = 128; k > 0; k >>= 1) { if (t < k) red[t] += red[t + k]; __syncthreads(); }
    float invS = 1.f / red[0];
    int r0 = b * SMR;
    if (t < SMR) wrow[t] = expf(scores[r0 + t] - M) * invS;
    __syncthreads();
    int j = t * 4;  // 1024 cols / 256 threads
    float4 acc = make_float4(0.f, 0.f, 0.f, 0.f);
    #pragma unroll
    for (int r = 0; r < SMR; ++r) {
        float w = wrow[r];
        float4 e = *(const float4*)(E + (size_t)(r0 + r) * HID + j);
        acc.x += w * e.x; acc.y += w * e.y; acc.z += w * e.z; acc.w += w * e.w;
    }
    *(float4*)(partials + (size_t)b * HID + j) = acc;
    if (b == 0) {
        #pragma unroll
        for (int i = 0; i < 8; ++i) out_w[t + 256 * i] = expf(v[i] - M) * invS;
    }
}

// K3: reduce SMB partial rows -> applied[1024]; one block per column,
// 256-way parallel loads (latency-hiding), LDS tree.
__global__ __launch_bounds__(256) void k_apply_reduce(
        const float* __restrict__ partials, float* __restrict__ applied) {
    __shared__ float sm[4];
    int t = threadIdx.x, j = blockIdx.x;
    float v = partials[(size_t)t * HID + j];
    v = wave_reduce_sum(v);
    int wib = t >> 6, lane = t & 63;
    if (lane == 0) sm[wib] = v;
    __syncthreads();
    if (t == 0) applied[j] = sm[0] + sm[1] + sm[2] + sm[3];
}

// K4: x = relu(comb_W @ cat(embedded, attn_applied) + comb_b); one wave per row
__global__ __launch_bounds__(256) void k_comb(
        const float* __restrict__ emb, const int* __restrict__ tok,
        const float* __restrict__ applied,
        const float* __restrict__ comb_W, const float* __restrict__ comb_b,
        float* __restrict__ x) {
    int gtid = blockIdx.x * blockDim.x + threadIdx.x;
    int row = gtid >> 6, lane = gtid & 63;
    if (row >= HID) return;
    const float* erow = emb + (size_t)tok[0] * HID;
    const float* wrow = comb_W + (size_t)row * (2 * HID);
    float acc = 0.f;
    #pragma unroll
    for (int i = 0; i < 8; ++i) {
        int k = i * 256 + lane * 4;
        float4 w = *(const float4*)(wrow + k);
        float4 c = (k < HID) ? *(const float4*)(erow + k)
                             : *(const float4*)(applied + (k - HID));
        acc += w.x * c.x + w.y * c.y + w.z * c.z + w.w * c.w;
    }
    acc = wave_reduce_sum(acc);
    if (lane == 0) x[row] = fmaxf(acc + comb_b[row], 0.f);
}

// K5: gi = W_ih@x + b_ih, gh = W_hh@h + b_hh; 6144 rows, one wave per row
__global__ __launch_bounds__(256) void k_gru_gemv(
        const float* __restrict__ W_ih, const float* __restrict__ W_hh,
        const float* __restrict__ b_ih, const float* __restrict__ b_hh,
        const float* __restrict__ x, const float* __restrict__ h,
        float* __restrict__ gi, float* __restrict__ gh) {
    int gtid = blockIdx.x * blockDim.x + threadIdx.x;
    int row = gtid >> 6, lane = gtid & 63;
    if (row >= 6 * HID) return;
    const float* wrow; const float* vec;
    if (row < 3 * HID) { wrow = W_ih + (size_t)row * HID; vec = x; }
    else               { wrow = W_hh + (size_t)(row - 3 * HID) * HID; vec = h; }
    float acc = 0.f;
    #pragma unroll
    for (int i = 0; i < 4; ++i) {
        int k = i * 256 + lane * 4;
        float4 w = *(const float4*)(wrow + k);
        float4 c = *(const float4*)(vec + k);
        acc += w.x * c.x + w.y * c.y + w.z * c.z + w.w * c.w;
    }
    acc = wave_reduce_sum(acc);
    if (lane == 0) {
        if (row < 3 * HID) gi[row] = acc + b_ih[row];
        else               gh[row - 3 * HID] = acc + b_hh[row - 3 * HID];
    }
}

// K6: GRU gates -> h_new (d_out + ws copy)
__global__ __launch_bounds__(256) void k_gru_gate(
        const float* __restrict__ gi, const float* __restrict__ gh,
        const float* __restrict__ h,
        float* __restrict__ hnew_out, float* __restrict__ hnew_ws) {
    int i = blockIdx.x * blockDim.x + threadIdx.x;
    float r = 1.f / (1.f + expf(-(gi[i] + gh[i])));
    float z = 1.f / (1.f + expf(-(gi[i + HID] + gh[i + HID])));
    float n = tanhf(gi[i + 2 * HID] + r * gh[i + 2 * HID]);
    float hn = (1.f - z) * n + z * h[i];
    hnew_out[i] = hn;
    hnew_ws[i]  = hn;
}

// K7: logits + per-block online-LSE (m,s). 8 waves/block, 2 rows/wave.
__global__ __launch_bounds__(512) void k_logits(
        const float* __restrict__ hnew, const float* __restrict__ out_W,
        const float* __restrict__ out_b,
        float* __restrict__ logits, float* __restrict__ pm, float* __restrict__ ps) {
    __shared__ float wm[8], wsum[8];
    int wib = threadIdx.x >> 6, lane = threadIdx.x & 63;
    int r0 = blockIdx.x * LROWS + wib * 2;
    bool v0 = r0 < VOCAB, v1 = (r0 + 1) < VOCAB;
    int rr0 = v0 ? r0 : 0, rr1 = v1 ? (r0 + 1) : 0;
    const float* w0 = out_W + (size_t)rr0 * HID;
    const float* w1 = out_W + (size_t)rr1 * HID;
    float acc0 = 0.f, acc1 = 0.f;
    #pragma unroll
    for (int i = 0; i < 4; ++i) {
        int k = i * 256 + lane * 4;
        float4 a = *(const float4*)(w0 + k);
        float4 b = *(const float4*)(w1 + k);
        float4 c = *(const float4*)(hnew + k);
        acc0 += a.x * c.x + a.y * c.y + a.z * c.z + a.w * c.w;
        acc1 += b.x * c.x + b.y * c.y + b.z * c.z + b.w * c.w;
    }
    acc0 = wave_reduce_sum(acc0);
    acc1 = wave_reduce_sum(acc1);
    if (lane == 0) {
        float l0 = acc0 + out_b[rr0], l1 = acc1 + out_b[rr1];
        if (v0) logits[r0] = l0;
        if (v1) logits[r0 + 1] = l1;
        float m, s;
        if (v0 | v1) {
            float e0 = v0 ? l0 : -INFINITY, e1 = v1 ? l1 : -INFINITY;
            m = fmaxf(e0, e1);
            s = (v0 ? expf(e0 - m) : 0.f) + (v1 ? expf(e1 - m) : 0.f);
        } else { m = -INFINITY; s = 0.f; }
        wm[wib] = m; wsum[wib] = s;
    }
    __syncthreads();
    if (threadIdx.x == 0) {
        float M = wm[0];
        #pragma unroll
        for (int i = 1; i < 8; ++i) M = fmaxf(M, wm[i]);
        float S = 0.f;
        #pragma unroll
        for (int i = 0; i < 8; ++i) S += (wsum[i] > 0.f) ? wsum[i] * expf(wm[i] - M) : 0.f;
        pm[blockIdx.x] = M;
        ps[blockIdx.x] = S;
    }
}

// K8: every block redundantly merges the LBLK (m,s) pairs (bit-identical ->
// deterministic), then writes out[v] = logits[v] - lse for its slice.
__global__ __launch_bounds__(256) void k_logsoftmax_write(
        const float* __restrict__ pm, const float* __restrict__ ps,
        float* __restrict__ out) {
    __shared__ float red[256];
    int t = threadIdx.x;
    float m = -INFINITY;
    for (int i = t; i < LBLK; i += 256) m = fmaxf(m, pm[i]);
    red[t] = m; __syncthreads();
    for (int s = 128; s > 0; s >>= 1) { if (t < s) red[t] = fmaxf(red[t], red[t + s]); __syncthreads(); }
    float M = red[0]; __syncthreads();
    float acc = 0.f;
    for (int i = t; i < LBLK; i += 256) acc += ps[i] * expf(pm[i] - M);
    red[t] = acc; __syncthreads();
    for (int s = 128; s > 0; s >>= 1) { if (t < s) red[t] += red[t + s]; __syncthreads(); }
    float lse = M + logf(red[0]);
    int v = blockIdx.x * 256 + t;
    if (v < VOCAB) out[v] -= lse;
}

extern "C" void kernel_launch(void* const* d_in, const int* in_sizes, int n_in,
                              void* d_out, int out_size, void* d_ws, size_t ws_size,
                              hipStream_t stream) {
    const int*   tok     = (const int*)d_in[0];
    const float* hidden  = (const float*)d_in[1];
    const float* E       = (const float*)d_in[2];
    const float* emb     = (const float*)d_in[3];
    const float* attn_W  = (const float*)d_in[4];
    const float* attn_b  = (const float*)d_in[5];
    const float* comb_W  = (const float*)d_in[6];
    const float* comb_b  = (const float*)d_in[7];
    const float* W_ih    = (const float*)d_in[8];
    const float* W_hh    = (const float*)d_in[9];
    const float* b_ih    = (const float*)d_in[10];
    const float* b_hh    = (const float*)d_in[11];
    const float* out_W   = (const float*)d_in[12];
    const float* out_b   = (const float*)d_in[13];

    float* out       = (float*)d_out;          // [0, VOCAB): log-probs
    float* hnew_out  = out + VOCAB;            // h_new
    float* attnw_out = out + VOCAB + HID;      // attn_weights

    float* ws        = (float*)d_ws;
    float* scores    = ws + WS_SCORES;
    float* applied   = ws + WS_APPLIED;
    float* x         = ws + WS_X;
    float* gi        = ws + WS_GI;
    float* gh        = ws + WS_GH;
    float* hnew_ws   = ws + WS_HNEW;
    float* pm        = ws + WS_PM;
    float* ps        = ws + WS_PS;
    float* partials  = ws + WS_PARTIALS;

    k_attn_scores<<<MAXLEN / 4, 256, 0, stream>>>(emb, tok, hidden, attn_W, attn_b, scores);
    k_softmax_apply<<<SMB, 256, 0, stream>>>(scores, E, attnw_out, partials);
    k_apply_reduce<<<HID, 256, 0, stream>>>(partials, applied);
    k_comb<<<HID / 4, 256, 0, stream>>>(emb, tok, applied, comb_W, comb_b, x);
    k_gru_gemv<<<(6 * HID) / 4, 256, 0, stream>>>(W_ih, W_hh, b_ih, b_hh, x, hidden, gi, gh);
    k_gru_gate<<<HID / 256, 256, 0, stream>>>(gi, gh, hidden, hnew_out, hnew_ws);
    k_logits<<<LBLK, 512, 0, stream>>>(hnew_ws, out_W, out_b, out, pm, ps);
    k_logsoftmax_write<<<(VOCAB + 255) / 256, 256, 0, stream>>>(pm, ps, out);
}